// Round 15
// baseline (236.808 us; speedup 1.0000x reference)
//
#include <hip/hip_runtime.h>
#include <cstdint>
#include <cstddef>

// GATv2 x2. Round 15: GEMM tile 128x256 (gemm0 single col-block: A staged
// once; gemm1 A re-stage halved; 2x MFMA per barrier), cntp stride 32->16,
// gat0 pipeline D=6 (L2-resident regime). gat1 untouched (at gather wall).
// 7 dispatches + 1 memset. N=50000, E=800000, H=2, C_IN=256, C1=64, C2=128.

#define NEG_SLOPE 0.2f

typedef _Float16 f16x8 __attribute__((ext_vector_type(8)));
typedef _Float16 f16x4 __attribute__((ext_vector_type(4)));
typedef _Float16 f16x2 __attribute__((ext_vector_type(2)));
typedef float f32x4 __attribute__((ext_vector_type(4)));

#if __has_builtin(__builtin_amdgcn_exp2f)
#define EXP2(x) __builtin_amdgcn_exp2f(x)
#else
#define EXP2(x) __expf((x)*0.69314718056f)
#endif

#define DPPADD(x, CTRL)                                                        \
  do {                                                                         \
    int _y = __builtin_amdgcn_update_dpp(0, __float_as_int(x), CTRL, 0xf, 0xf, \
                                         true);                                \
    x += __int_as_float(_y);                                                   \
  } while (0)

#if __has_builtin(__builtin_amdgcn_global_load_lds)
#define STAGE16(gp, lbase, lane)                                               \
  __builtin_amdgcn_global_load_lds(                                            \
      (const __attribute__((address_space(1))) void*)(gp),                     \
      (__attribute__((address_space(3))) void*)(lbase), 16, 0, 0)
#else
#define STAGE16(gp, lbase, lane)                                               \
  *(f16x8*)((lbase) + (size_t)(lane) * 8) = *(const f16x8*)(gp)
#endif

// ---------------------------------------------------------------------------
// Fused setup: [cast x->f16] + [W0^T cast] + [W1^T cast] + [count+pos].
// cntp padded: one counter per 64B line; pre-zeroed by memset.
__global__ __launch_bounds__(256) void setup_fused(
    const float* __restrict__ x, _Float16* __restrict__ xa,
    const float* __restrict__ Wl0, const float* __restrict__ Wr0,
    _Float16* __restrict__ Bt0,
    const float* __restrict__ Wl1, const float* __restrict__ Wr1,
    _Float16* __restrict__ Bt1,
    const int* __restrict__ ei, int E, int* __restrict__ cntp,
    int* __restrict__ pos, int nb_cast, int N) {
  const int b = blockIdx.x;
  if (b < nb_cast) {
    const int t = b * 256 + threadIdx.x;
    if (t < N * 64) {
      const float4 v = *(const float4*)&x[(size_t)t * 4];
      f16x4 h;
      h[0] = (_Float16)v.x; h[1] = (_Float16)v.y;
      h[2] = (_Float16)v.z; h[3] = (_Float16)v.w;
      *(f16x4*)&xa[(size_t)t * 4] = h;
    }
  } else if (b < nb_cast + 256) {
    const int t = (b - nb_cast) * 256 + threadIdx.x;   // 0..65535
    const int n = t >> 8, k = t & 255;                 // K=256, NH=128
    const float v = (n < 128) ? Wl0[(size_t)k * 128 + n]
                              : Wr0[(size_t)k * 128 + (n - 128)];
    Bt0[t] = (_Float16)v;
  } else if (b < nb_cast + 512) {
    const int t = (b - nb_cast - 256) * 256 + threadIdx.x;  // 0..65535
    const int n = t >> 7, k = t & 127;                 // K=128, NH=256
    const float v = (n < 256) ? Wl1[(size_t)k * 256 + n]
                              : Wr1[(size_t)k * 256 + (n - 256)];
    Bt1[t] = (_Float16)v;
  } else {
    const int i = (b - nb_cast - 512) * 256 + threadIdx.x;
    if (i < E) {
      const int dst = ei[E + i];
      pos[i] = atomicAdd(&cntp[dst * 16], 1);   // 64B-line-private counter
    }
  }
}

// ---------------------------------------------------------------------------
// Shared GEMM body: 128x256 tile, BK=64, 4 waves (each 64x128 out).
// f16 A/B via global_load_lds, XOR-swizzled source chunk + same XOR on
// ds_read. A rows padded (Mpad); B rows = NT (multiple of 256).
__device__ __forceinline__ void hgemm_body(
    const _Float16* __restrict__ A, const _Float16* __restrict__ Bt,
    _Float16* __restrict__ C, int M, int NT, int K, int bm, int bn) {
  __shared__ _Float16 As[128 * 64];   // 16 KB
  __shared__ _Float16 Bs[256 * 64];   // 32 KB
  const int tid = threadIdx.x;
  const int lane = tid & 63;
  const int wave = tid >> 6;
  const int wr = (wave >> 1) * 64;    // wave row offset (0/64)
  const int wcol = (wave & 1) * 128;  // wave col offset (0/128)
  const int l15 = lane & 15;
  const int kq8 = lane >> 4;
  const int srow = lane >> 3;
  const int swz = (lane & 7) ^ srow;
  f32x4 acc[4][8] = {};
  for (int k0 = 0; k0 < K; k0 += 64) {
    __syncthreads();
#pragma unroll
    for (int i = 0; i < 4; ++i) {     // A rows: wave*32 + i*8 + srow
      const int r = wave * 32 + i * 8;
      const _Float16* gp = A + (size_t)(bm + r + srow) * K + k0 + swz * 8;
      STAGE16(gp, As + r * 64, lane);
    }
#pragma unroll
    for (int i = 0; i < 8; ++i) {     // B rows: wave*64 + i*8 + srow
      const int r = wave * 64 + i * 8;
      const _Float16* gp = Bt + (size_t)(bn + r + srow) * K + k0 + swz * 8;
      STAGE16(gp, Bs + r * 64, lane);
    }
    __syncthreads();
#pragma unroll
    for (int kk = 0; kk < 64; kk += 32) {
      const int oc = kq8 + (kk >> 3);
      f16x8 bf[8];
#pragma unroll
      for (int ni = 0; ni < 8; ++ni) {
        const int row = wcol + ni * 16 + l15;
        bf[ni] = *(const f16x8*)&Bs[row * 64 + ((oc ^ (row & 7)) << 3)];
      }
#pragma unroll
      for (int mi = 0; mi < 4; ++mi) {
        const int row = wr + mi * 16 + l15;
        const f16x8 af = *(const f16x8*)&As[row * 64 + ((oc ^ (row & 7)) << 3)];
#pragma unroll
        for (int ni = 0; ni < 8; ++ni)
          acc[mi][ni] = __builtin_amdgcn_mfma_f32_16x16x32_f16(af, bf[ni], acc[mi][ni], 0, 0, 0);
      }
    }
  }
  const int crow0 = (lane >> 4) * 4;
#pragma unroll
  for (int mi = 0; mi < 4; ++mi) {
#pragma unroll
    for (int r = 0; r < 4; ++r) {
      const int row = bm + wr + mi * 16 + crow0 + r;
      if (row < M) {
#pragma unroll
        for (int ni = 0; ni < 8; ++ni)
          C[(size_t)row * NT + bn + wcol + ni * 16 + l15] = (_Float16)acc[mi][ni][r];
      }
    }
  }
}

__global__ __launch_bounds__(256) void hgemm_tn(
    const _Float16* __restrict__ A, const _Float16* __restrict__ Bt,
    _Float16* __restrict__ C, int M, int NT, int K) {
  hgemm_body(A, Bt, C, M, NT, K, blockIdx.y * 128, blockIdx.x * 256);
}

// csr_fill (atomic-free: precomputed pos) first, then gemm0 blocks
// (NT=256 -> single col-block per row-block).
__global__ __launch_bounds__(256) void gemm_fill(
    const _Float16* __restrict__ A, const _Float16* __restrict__ Bt,
    _Float16* __restrict__ C, int M, int NT, int K,
    const int* __restrict__ ei, int E, int EA,
    const int* __restrict__ rowptr, const int* __restrict__ pos,
    int* __restrict__ col, int gFill) {
  if ((int)blockIdx.x < gFill) {
    const int i = blockIdx.x * 256 + threadIdx.x;
    if (i < EA) {
      if (i < E) {
        const int src = ei[i], dst = ei[E + i];
        col[rowptr[dst] + pos[i]] = src;        // scattered write, no atomic
      } else {
        const int n2 = i - E;                   // self-loop -> reserved last slot
        col[rowptr[n2 + 1] - 1] = n2;
      }
    }
    return;
  }
  const int b2 = blockIdx.x - gFill;
  hgemm_body(A, Bt, C, M, NT, K, b2 * 128, 0);
}

// ---------------------------------------------------------------------------
// CSR scan (2-dispatch form). Degree = cntp[i*16] + 1 (self-loop).
__global__ __launch_bounds__(256) void scan_block(
    const int* __restrict__ cntp, int* __restrict__ excl,
    int* __restrict__ bsum, int n) {
  __shared__ int s[256];
  const int tid = threadIdx.x;
  const int i = blockIdx.x * 256 + tid;
  const int v = (i < n) ? (cntp[i * 16] + 1) : 0;
  s[tid] = v;
  __syncthreads();
  for (int off = 1; off < 256; off <<= 1) {
    const int t = (tid >= off) ? s[tid - off] : 0;
    __syncthreads();
    s[tid] += t;
    __syncthreads();
  }
  if (i < n) excl[i] = s[tid] - v;
  if (tid == 255) bsum[blockIdx.x] = s[255];
}

__global__ __launch_bounds__(256) void scan_add(
    int* __restrict__ rowptr, const int* __restrict__ bsum, int n, int EA) {
  __shared__ int s[256];
  const int tid = threadIdx.x;
  s[tid] = (tid < (int)blockIdx.x) ? bsum[tid] : 0;
  __syncthreads();
#pragma unroll
  for (int off = 128; off; off >>= 1) {
    if (tid < off) s[tid] += s[tid + off];
    __syncthreads();
  }
  const int add = s[0];
  const int i = blockIdx.x * 256 + tid;
  if (i < n) rowptr[i] += add;
  if (i == 0) rowptr[n] = EA;
}

// ---------------------------------------------------------------------------
// Fused per-node GATv2, 2 edges per wave. Plain launch_bounds(256) — the
// (256,8) variant capped VGPR 40->32 and spilled (R11, +55us/kernel).
template <int C, int LOGS, int V, int D, bool RELU, bool OUT16>
__global__ __launch_bounds__(256) void fused_gat_h2(
    const int* __restrict__ rowptr, const int* __restrict__ col,
    const _Float16* __restrict__ feat, const float* __restrict__ att,
    const float* __restrict__ bias, _Float16* __restrict__ out16,
    float* __restrict__ out32, int N) {
  constexpr int P = V / 2;
  typedef _Float16 hv __attribute__((ext_vector_type(V)));
  const int n = blockIdx.x * 4 + (threadIdx.x >> 6);
  if (n >= N) return;
  const int lane = threadIdx.x & 63;
  const int half = lane >> 5;
  const int li = lane & 31;
  const int co = li * V;

  f16x2 xr2[P], at2[P];
  float O[V];
  {
    const int base = (n << LOGS) + 2 * C + co;
#pragma unroll
    for (int p = 0; p < P; ++p) xr2[p] = *(const f16x2*)&feat[base + 2 * p];
#pragma unroll
    for (int p = 0; p < P; ++p)
      at2[p] = f16x2{(_Float16)(att[co + 2 * p] * 1.44269504f),
                     (_Float16)(att[co + 2 * p + 1] * 1.44269504f)};
#pragma unroll
    for (int j = 0; j < V; ++j) O[j] = 0.f;
  }
  float m = -1e30f, l = 0.f;
  const int e0 = rowptr[n], e1 = rowptr[n + 1];
  const int e1m1 = e1 - 1;

  hv f[D];
  int cidx[D];
#pragma unroll
  for (int k = 0; k < D; ++k) {
    const int ek = e0 + 2 * k + half;
    const int ck = col[(ek < e1) ? ek : e1m1];
    f[k] = *(const hv*)&feat[(ck << LOGS) + co];
  }
#pragma unroll
  for (int k = 0; k < D; ++k) {
    const int ek = e0 + 2 * k + half + 2 * D;
    cidx[k] = col[(ek < e1) ? ek : e1m1];
  }

  for (int ebase = e0; ebase < e1; ebase += 2 * D) {
#pragma unroll
    for (int k = 0; k < D; ++k) {
      const int eid = ebase + 2 * k + half;
      const bool valid = eid < e1;
      float pacc = 0.f;
#pragma unroll
      for (int p = 0; p < P; ++p) {
        const f16x2 c2 = f16x2{f[k][2 * p], f[k][2 * p + 1]};
        const f16x2 s = c2 + xr2[p];
        const f16x2 mx = __builtin_elementwise_max(s, f16x2{(_Float16)0.f, (_Float16)0.f});
        const f16x2 mn = __builtin_elementwise_min(s, f16x2{(_Float16)0.f, (_Float16)0.f});
        const f16x2 lk = mn * f16x2{(_Float16)NEG_SLOPE, (_Float16)NEG_SLOPE} + mx;
        pacc = __builtin_amdgcn_fdot2(lk, at2[p], pacc, false);
      }
      DPPADD(pacc, 0xB1);
      DPPADD(pacc, 0x4E);
      DPPADD(pacc, 0x124);
      DPPADD(pacc, 0x128);
      if (!valid) pacc = -INFINITY;
      if (__any(pacc - m > 11.54f)) {
        const float mn2 = fmaxf(m, pacc);
        const float scale = EXP2(m - mn2);
        const float w = EXP2(pacc - mn2);
        l = l * scale + w;
#pragma unroll
        for (int j = 0; j < V; ++j) O[j] = O[j] * scale + w * (float)f[k][j];
        m = mn2;
      } else {
        const float w = EXP2(pacc - m);
        l += w;
#pragma unroll
        for (int j = 0; j < V; ++j) O[j] += w * (float)f[k][j];
      }
      f[k] = *(const hv*)&feat[(cidx[k] << LOGS) + co];
      const int enn = eid + 4 * D;
      cidx[k] = col[(enn < e1) ? enn : e1m1];
    }
  }

  {
    const float m2 = __shfl_xor(m, 32, 64);
    const float l2 = __shfl_xor(l, 32, 64);
    const float mn = fmaxf(m, m2);
    const float s1 = EXP2(m - mn);
    const float s2 = EXP2(m2 - mn);
    l = l * s1 + l2 * s2;
#pragma unroll
    for (int j = 0; j < V; ++j)
      O[j] = O[j] * s1 + __shfl_xor(O[j], 32, 64) * s2;
  }
  if (half) return;

  const float inv = 1.f / l;
  if constexpr (OUT16) {
    typedef _Float16 ov __attribute__((ext_vector_type(V)));
    ov o;
#pragma unroll
    for (int j = 0; j < V; ++j) {
      float v = O[j] * inv + bias[co + j];
      if constexpr (RELU) v = fmaxf(v, 0.f);
      o[j] = (_Float16)v;
    }
    *(ov*)&out16[n * (2 * C) + co] = o;
  } else {
#pragma unroll
    for (int q = 0; q < V / 4; ++q) {
      float4 o;
      o.x = O[q * 4 + 0] * inv + bias[co + q * 4 + 0];
      o.y = O[q * 4 + 1] * inv + bias[co + q * 4 + 1];
      o.z = O[q * 4 + 2] * inv + bias[co + q * 4 + 2];
      o.w = O[q * 4 + 3] * inv + bias[co + q * 4 + 3];
      *(float4*)&out32[(size_t)n * (2 * C) + co + q * 4] = o;
    }
  }
}

// ---------------------------------------------------------------------------
extern "C" void kernel_launch(void* const* d_in, const int* in_sizes, int n_in,
                              void* d_out, int out_size, void* d_ws, size_t ws_size,
                              hipStream_t stream) {
  const float* x    = (const float*)d_in[0];
  const int*   ei   = (const int*)d_in[1];
  const float* Wl0  = (const float*)d_in[2];
  const float* Wr0  = (const float*)d_in[3];
  const float* att0 = (const float*)d_in[4];
  const float* b0   = (const float*)d_in[5];
  const float* Wl1  = (const float*)d_in[6];
  const float* Wr1  = (const float*)d_in[7];
  const float* att1 = (const float*)d_in[8];
  const float* b1   = (const float*)d_in[9];
  float* out = (float*)d_out;

  const int N    = in_sizes[0] / 256;
  const int E    = in_sizes[1] / 2;
  const int EA   = E + N;
  const int Mpad = (N + 127) & ~127;

  _Float16* hw    = (_Float16*)d_ws;
  _Float16* feat0 = hw;                       // N x 256 (overlapped by feat1)
  _Float16* feat1 = hw;                       // N x 512
  _Float16* ha    = hw + (size_t)N * 512;     // Mpad x 128 (L0 out, f16)
  _Float16* xa    = ha + (size_t)Mpad * 128;  // Mpad x 256 (x in f16)
  _Float16* Bt0   = xa + (size_t)Mpad * 256;  // 256 x 256
  _Float16* Bt1   = Bt0 + 65536;              // 512 x 128
  int* rowptr = (int*)(Bt1 + 65536);
  const int cpad = (N + 1 + 3) & ~3;
  int* cntp   = rowptr + cpad;                // [N*16] padded counters
  int* bsum   = cntp + (size_t)N * 16;        // [256]
  int* pos    = bsum + 256;                   // [E]
  int* col    = pos + E;                      // [EA]

  const dim3 blk(256);
  const int gE      = (E + 255) / 256;
  const int gEA     = (EA + 255) / 256;
  const int gScan   = (N + 255) / 256;
  const int gM      = Mpad / 128;
  const int gNode   = (N + 3) / 4;
  const int nb_cast = (N * 64 + 255) / 256;

  // 1) zero padded counters
  hipMemsetAsync(cntp, 0, (size_t)N * 16 * 4, stream);
  // 2) fused setup: cast x, transpose+cast W0/W1, count+pos (1 atomic/edge)
  setup_fused<<<nb_cast + 512 + gE, blk, 0, stream>>>(
      x, xa, Wl0, Wr0, Bt0, Wl1, Wr1, Bt1, ei, E, cntp, pos, nb_cast, N);
  // 3-4) scan (degree = cntp[i*16]+1)
  scan_block<<<gScan, blk, 0, stream>>>(cntp, rowptr, bsum, N);
  scan_add<<<gScan, blk, 0, stream>>>(rowptr, bsum, N, EA);
  // 5) atomic-free csr_fill (first gEA blocks) + gemm0 (128x256, 1 col-block)
  gemm_fill<<<gEA + gM, blk, 0, stream>>>(
      xa, Bt0, feat0, N, 256, 256, ei, E, EA, rowptr, pos, col, gEA);
  // 6) gat0 (C=64, LOGS=8, V=4, D=6)
  fused_gat_h2<64, 8, 4, 6, true, true><<<gNode, blk, 0, stream>>>(
      rowptr, col, feat0, att0, b0, ha, nullptr, N);
  // 7) gemm1 (128x256 tile -> 2 col-blocks)
  hgemm_tn<<<dim3(2, gM), blk, 0, stream>>>(ha, Bt1, feat1, N, 512, 128);
  // 8) gat1 (C=128, LOGS=9, V=8, D=4)
  fused_gat_h2<128, 9, 8, 4, false, false><<<gNode, blk, 0, stream>>>(
      rowptr, col, feat1, att1, b1, nullptr, out, N);
}

// Round 16
// 219.732 us; speedup vs baseline: 1.0777x; 1.0777x over previous
//
#include <hip/hip_runtime.h>
#include <cstdint>
#include <cstddef>

// GATv2 x2. Round 16: exact revert to R14 (proven 220.5us): GEMM 128x128
// BK=64 acc[4][4], gat0 D=4, cntp stride 32, atomic-free fill.
// 7 dispatches + 1 memset. N=50000, E=800000, H=2, C_IN=256, C1=64, C2=128.

#define NEG_SLOPE 0.2f

typedef _Float16 f16x8 __attribute__((ext_vector_type(8)));
typedef _Float16 f16x4 __attribute__((ext_vector_type(4)));
typedef _Float16 f16x2 __attribute__((ext_vector_type(2)));
typedef float f32x4 __attribute__((ext_vector_type(4)));

#if __has_builtin(__builtin_amdgcn_exp2f)
#define EXP2(x) __builtin_amdgcn_exp2f(x)
#else
#define EXP2(x) __expf((x)*0.69314718056f)
#endif

#define DPPADD(x, CTRL)                                                        \
  do {                                                                         \
    int _y = __builtin_amdgcn_update_dpp(0, __float_as_int(x), CTRL, 0xf, 0xf, \
                                         true);                                \
    x += __int_as_float(_y);                                                   \
  } while (0)

#if __has_builtin(__builtin_amdgcn_global_load_lds)
#define STAGE16(gp, lbase, lane)                                               \
  __builtin_amdgcn_global_load_lds(                                            \
      (const __attribute__((address_space(1))) void*)(gp),                     \
      (__attribute__((address_space(3))) void*)(lbase), 16, 0, 0)
#else
#define STAGE16(gp, lbase, lane)                                               \
  *(f16x8*)((lbase) + (size_t)(lane) * 8) = *(const f16x8*)(gp)
#endif

// ---------------------------------------------------------------------------
// Fused setup: [cast x->f16] + [W0^T cast] + [W1^T cast] + [count+pos].
// cntp is padded (one counter per 128B line); pre-zeroed by memset.
__global__ __launch_bounds__(256) void setup_fused(
    const float* __restrict__ x, _Float16* __restrict__ xa,
    const float* __restrict__ Wl0, const float* __restrict__ Wr0,
    _Float16* __restrict__ Bt0,
    const float* __restrict__ Wl1, const float* __restrict__ Wr1,
    _Float16* __restrict__ Bt1,
    const int* __restrict__ ei, int E, int* __restrict__ cntp,
    int* __restrict__ pos, int nb_cast, int N) {
  const int b = blockIdx.x;
  if (b < nb_cast) {
    const int t = b * 256 + threadIdx.x;
    if (t < N * 64) {
      const float4 v = *(const float4*)&x[(size_t)t * 4];
      f16x4 h;
      h[0] = (_Float16)v.x; h[1] = (_Float16)v.y;
      h[2] = (_Float16)v.z; h[3] = (_Float16)v.w;
      *(f16x4*)&xa[(size_t)t * 4] = h;
    }
  } else if (b < nb_cast + 256) {
    const int t = (b - nb_cast) * 256 + threadIdx.x;   // 0..65535
    const int n = t >> 8, k = t & 255;                 // K=256, NH=128
    const float v = (n < 128) ? Wl0[(size_t)k * 128 + n]
                              : Wr0[(size_t)k * 128 + (n - 128)];
    Bt0[t] = (_Float16)v;
  } else if (b < nb_cast + 512) {
    const int t = (b - nb_cast - 256) * 256 + threadIdx.x;  // 0..65535
    const int n = t >> 7, k = t & 127;                 // K=128, NH=256
    const float v = (n < 256) ? Wl1[(size_t)k * 256 + n]
                              : Wr1[(size_t)k * 256 + (n - 256)];
    Bt1[t] = (_Float16)v;
  } else {
    const int i = (b - nb_cast - 512) * 256 + threadIdx.x;
    if (i < E) {
      const int dst = ei[E + i];
      pos[i] = atomicAdd(&cntp[dst * 32], 1);   // line-private counter
    }
  }
}

// ---------------------------------------------------------------------------
// Shared GEMM body: 128x128 tile, BK=64, 4 waves (64x64 out each). f16 A/B
// via global_load_lds, XOR-swizzled source chunk + same XOR on ds_read.
__device__ __forceinline__ void hgemm_body(
    const _Float16* __restrict__ A, const _Float16* __restrict__ Bt,
    _Float16* __restrict__ C, int M, int NT, int K, int bm, int bn) {
  __shared__ _Float16 As[128 * 64];
  __shared__ _Float16 Bs[128 * 64];
  const int tid = threadIdx.x;
  const int lane = tid & 63;
  const int wave = tid >> 6;
  const int wr = (wave >> 1) * 64;
  const int wcol = (wave & 1) * 64;
  const int l15 = lane & 15;
  const int kq8 = lane >> 4;
  const int srow = lane >> 3;
  const int swz = (lane & 7) ^ srow;
  f32x4 acc[4][4] = {};
  for (int k0 = 0; k0 < K; k0 += 64) {
    __syncthreads();
#pragma unroll
    for (int i = 0; i < 4; ++i) {
      const int r = wave * 32 + i * 8;
      const _Float16* gp = A + (size_t)(bm + r + srow) * K + k0 + swz * 8;
      STAGE16(gp, As + r * 64, lane);
    }
#pragma unroll
    for (int i = 0; i < 4; ++i) {
      const int r = wave * 32 + i * 8;
      const _Float16* gp = Bt + (size_t)(bn + r + srow) * K + k0 + swz * 8;
      STAGE16(gp, Bs + r * 64, lane);
    }
    __syncthreads();
#pragma unroll
    for (int kk = 0; kk < 64; kk += 32) {
      const int oc = kq8 + (kk >> 3);
      f16x8 bf[4];
#pragma unroll
      for (int ni = 0; ni < 4; ++ni) {
        const int row = wcol + ni * 16 + l15;
        bf[ni] = *(const f16x8*)&Bs[row * 64 + ((oc ^ (row & 7)) << 3)];
      }
#pragma unroll
      for (int mi = 0; mi < 4; ++mi) {
        const int row = wr + mi * 16 + l15;
        const f16x8 af = *(const f16x8*)&As[row * 64 + ((oc ^ (row & 7)) << 3)];
#pragma unroll
        for (int ni = 0; ni < 4; ++ni)
          acc[mi][ni] = __builtin_amdgcn_mfma_f32_16x16x32_f16(af, bf[ni], acc[mi][ni], 0, 0, 0);
      }
    }
  }
  const int crow0 = (lane >> 4) * 4;
#pragma unroll
  for (int mi = 0; mi < 4; ++mi) {
#pragma unroll
    for (int r = 0; r < 4; ++r) {
      const int row = bm + wr + mi * 16 + crow0 + r;
      if (row < M) {
#pragma unroll
        for (int ni = 0; ni < 4; ++ni)
          C[(size_t)row * NT + bn + wcol + ni * 16 + l15] = (_Float16)acc[mi][ni][r];
      }
    }
  }
}

__global__ __launch_bounds__(256) void hgemm_tn(
    const _Float16* __restrict__ A, const _Float16* __restrict__ Bt,
    _Float16* __restrict__ C, int M, int NT, int K) {
  hgemm_body(A, Bt, C, M, NT, K, blockIdx.y * 128, blockIdx.x * 128);
}

// csr_fill (ATOMIC-FREE: precomputed pos) first, then gemm0 blocks.
__global__ __launch_bounds__(256) void gemm_fill(
    const _Float16* __restrict__ A, const _Float16* __restrict__ Bt,
    _Float16* __restrict__ C, int M, int NT, int K,
    const int* __restrict__ ei, int E, int EA,
    const int* __restrict__ rowptr, const int* __restrict__ pos,
    int* __restrict__ col, int gFill) {
  if ((int)blockIdx.x < gFill) {
    const int i = blockIdx.x * 256 + threadIdx.x;
    if (i < EA) {
      if (i < E) {
        const int src = ei[i], dst = ei[E + i];
        col[rowptr[dst] + pos[i]] = src;        // scattered write, no atomic
      } else {
        const int n2 = i - E;                   // self-loop -> reserved last slot
        col[rowptr[n2 + 1] - 1] = n2;
      }
    }
    return;
  }
  const int b2 = blockIdx.x - gFill;
  hgemm_body(A, Bt, C, M, NT, K, (b2 >> 1) * 128, (b2 & 1) * 128);
}

// ---------------------------------------------------------------------------
// CSR scan (2-dispatch form). Degree = cntp[i*32] + 1 (self-loop).
__global__ __launch_bounds__(256) void scan_block(
    const int* __restrict__ cntp, int* __restrict__ excl,
    int* __restrict__ bsum, int n) {
  __shared__ int s[256];
  const int tid = threadIdx.x;
  const int i = blockIdx.x * 256 + tid;
  const int v = (i < n) ? (cntp[i * 32] + 1) : 0;
  s[tid] = v;
  __syncthreads();
  for (int off = 1; off < 256; off <<= 1) {
    const int t = (tid >= off) ? s[tid - off] : 0;
    __syncthreads();
    s[tid] += t;
    __syncthreads();
  }
  if (i < n) excl[i] = s[tid] - v;
  if (tid == 255) bsum[blockIdx.x] = s[255];
}

__global__ __launch_bounds__(256) void scan_add(
    int* __restrict__ rowptr, const int* __restrict__ bsum, int n, int EA) {
  __shared__ int s[256];
  const int tid = threadIdx.x;
  s[tid] = (tid < (int)blockIdx.x) ? bsum[tid] : 0;
  __syncthreads();
#pragma unroll
  for (int off = 128; off; off >>= 1) {
    if (tid < off) s[tid] += s[tid + off];
    __syncthreads();
  }
  const int add = s[0];
  const int i = blockIdx.x * 256 + tid;
  if (i < n) rowptr[i] += add;
  if (i == 0) rowptr[n] = EA;
}

// ---------------------------------------------------------------------------
// Fused per-node GATv2, 2 edges per wave. Plain launch_bounds(256) — the
// (256,8) variant capped VGPR 40->32 and spilled (R11, +55us/kernel).
template <int C, int LOGS, int V, int D, bool RELU, bool OUT16>
__global__ __launch_bounds__(256) void fused_gat_h2(
    const int* __restrict__ rowptr, const int* __restrict__ col,
    const _Float16* __restrict__ feat, const float* __restrict__ att,
    const float* __restrict__ bias, _Float16* __restrict__ out16,
    float* __restrict__ out32, int N) {
  constexpr int P = V / 2;
  typedef _Float16 hv __attribute__((ext_vector_type(V)));
  const int n = blockIdx.x * 4 + (threadIdx.x >> 6);
  if (n >= N) return;
  const int lane = threadIdx.x & 63;
  const int half = lane >> 5;
  const int li = lane & 31;
  const int co = li * V;

  f16x2 xr2[P], at2[P];
  float O[V];
  {
    const int base = (n << LOGS) + 2 * C + co;
#pragma unroll
    for (int p = 0; p < P; ++p) xr2[p] = *(const f16x2*)&feat[base + 2 * p];
#pragma unroll
    for (int p = 0; p < P; ++p)
      at2[p] = f16x2{(_Float16)(att[co + 2 * p] * 1.44269504f),
                     (_Float16)(att[co + 2 * p + 1] * 1.44269504f)};
#pragma unroll
    for (int j = 0; j < V; ++j) O[j] = 0.f;
  }
  float m = -1e30f, l = 0.f;
  const int e0 = rowptr[n], e1 = rowptr[n + 1];
  const int e1m1 = e1 - 1;

  hv f[D];
  int cidx[D];
#pragma unroll
  for (int k = 0; k < D; ++k) {
    const int ek = e0 + 2 * k + half;
    const int ck = col[(ek < e1) ? ek : e1m1];
    f[k] = *(const hv*)&feat[(ck << LOGS) + co];
  }
#pragma unroll
  for (int k = 0; k < D; ++k) {
    const int ek = e0 + 2 * k + half + 2 * D;
    cidx[k] = col[(ek < e1) ? ek : e1m1];
  }

  for (int ebase = e0; ebase < e1; ebase += 2 * D) {
#pragma unroll
    for (int k = 0; k < D; ++k) {
      const int eid = ebase + 2 * k + half;
      const bool valid = eid < e1;
      float pacc = 0.f;
#pragma unroll
      for (int p = 0; p < P; ++p) {
        const f16x2 c2 = f16x2{f[k][2 * p], f[k][2 * p + 1]};
        const f16x2 s = c2 + xr2[p];
        const f16x2 mx = __builtin_elementwise_max(s, f16x2{(_Float16)0.f, (_Float16)0.f});
        const f16x2 mn = __builtin_elementwise_min(s, f16x2{(_Float16)0.f, (_Float16)0.f});
        const f16x2 lk = mn * f16x2{(_Float16)NEG_SLOPE, (_Float16)NEG_SLOPE} + mx;
        pacc = __builtin_amdgcn_fdot2(lk, at2[p], pacc, false);
      }
      DPPADD(pacc, 0xB1);
      DPPADD(pacc, 0x4E);
      DPPADD(pacc, 0x124);
      DPPADD(pacc, 0x128);
      if (!valid) pacc = -INFINITY;
      if (__any(pacc - m > 11.54f)) {
        const float mn2 = fmaxf(m, pacc);
        const float scale = EXP2(m - mn2);
        const float w = EXP2(pacc - mn2);
        l = l * scale + w;
#pragma unroll
        for (int j = 0; j < V; ++j) O[j] = O[j] * scale + w * (float)f[k][j];
        m = mn2;
      } else {
        const float w = EXP2(pacc - m);
        l += w;
#pragma unroll
        for (int j = 0; j < V; ++j) O[j] += w * (float)f[k][j];
      }
      f[k] = *(const hv*)&feat[(cidx[k] << LOGS) + co];
      const int enn = eid + 4 * D;
      cidx[k] = col[(enn < e1) ? enn : e1m1];
    }
  }

  {
    const float m2 = __shfl_xor(m, 32, 64);
    const float l2 = __shfl_xor(l, 32, 64);
    const float mn = fmaxf(m, m2);
    const float s1 = EXP2(m - mn);
    const float s2 = EXP2(m2 - mn);
    l = l * s1 + l2 * s2;
#pragma unroll
    for (int j = 0; j < V; ++j)
      O[j] = O[j] * s1 + __shfl_xor(O[j], 32, 64) * s2;
  }
  if (half) return;

  const float inv = 1.f / l;
  if constexpr (OUT16) {
    typedef _Float16 ov __attribute__((ext_vector_type(V)));
    ov o;
#pragma unroll
    for (int j = 0; j < V; ++j) {
      float v = O[j] * inv + bias[co + j];
      if constexpr (RELU) v = fmaxf(v, 0.f);
      o[j] = (_Float16)v;
    }
    *(ov*)&out16[n * (2 * C) + co] = o;
  } else {
#pragma unroll
    for (int q = 0; q < V / 4; ++q) {
      float4 o;
      o.x = O[q * 4 + 0] * inv + bias[co + q * 4 + 0];
      o.y = O[q * 4 + 1] * inv + bias[co + q * 4 + 1];
      o.z = O[q * 4 + 2] * inv + bias[co + q * 4 + 2];
      o.w = O[q * 4 + 3] * inv + bias[co + q * 4 + 3];
      *(float4*)&out32[(size_t)n * (2 * C) + co + q * 4] = o;
    }
  }
}

// ---------------------------------------------------------------------------
extern "C" void kernel_launch(void* const* d_in, const int* in_sizes, int n_in,
                              void* d_out, int out_size, void* d_ws, size_t ws_size,
                              hipStream_t stream) {
  const float* x    = (const float*)d_in[0];
  const int*   ei   = (const int*)d_in[1];
  const float* Wl0  = (const float*)d_in[2];
  const float* Wr0  = (const float*)d_in[3];
  const float* att0 = (const float*)d_in[4];
  const float* b0   = (const float*)d_in[5];
  const float* Wl1  = (const float*)d_in[6];
  const float* Wr1  = (const float*)d_in[7];
  const float* att1 = (const float*)d_in[8];
  const float* b1   = (const float*)d_in[9];
  float* out = (float*)d_out;

  const int N    = in_sizes[0] / 256;
  const int E    = in_sizes[1] / 2;
  const int EA   = E + N;
  const int Mpad = (N + 127) & ~127;

  _Float16* hw    = (_Float16*)d_ws;
  _Float16* feat0 = hw;                       // N x 256 (overlapped by feat1)
  _Float16* feat1 = hw;                       // N x 512
  _Float16* ha    = hw + (size_t)N * 512;     // Mpad x 128 (L0 out, f16)
  _Float16* xa    = ha + (size_t)Mpad * 128;  // Mpad x 256 (x in f16)
  _Float16* Bt0   = xa + (size_t)Mpad * 256;  // 256 x 256
  _Float16* Bt1   = Bt0 + 65536;              // 512 x 128
  int* rowptr = (int*)(Bt1 + 65536);
  const int cpad = (N + 1 + 3) & ~3;
  int* cntp   = rowptr + cpad;                // [N*32] padded counters
  int* bsum   = cntp + (size_t)N * 32;        // [256]
  int* pos    = bsum + 256;                   // [E]
  int* col    = pos + E;                      // [EA]

  const dim3 blk(256);
  const int gE      = (E + 255) / 256;
  const int gEA     = (EA + 255) / 256;
  const int gScan   = (N + 255) / 256;
  const int gM      = Mpad / 128;
  const int gNode   = (N + 3) / 4;
  const int nb_cast = (N * 64 + 255) / 256;

  // 1) zero padded counters
  hipMemsetAsync(cntp, 0, (size_t)N * 32 * 4, stream);
  // 2) fused setup: cast x, transpose+cast W0/W1, count+pos (1 atomic/edge)
  setup_fused<<<nb_cast + 512 + gE, blk, 0, stream>>>(
      x, xa, Wl0, Wr0, Bt0, Wl1, Wr1, Bt1, ei, E, cntp, pos, nb_cast, N);
  // 3-4) scan (degree = cntp[i*32]+1)
  scan_block<<<gScan, blk, 0, stream>>>(cntp, rowptr, bsum, N);
  scan_add<<<gScan, blk, 0, stream>>>(rowptr, bsum, N, EA);
  // 5) atomic-free csr_fill (first gEA blocks) + gemm0
  gemm_fill<<<gEA + 2 * gM, blk, 0, stream>>>(
      xa, Bt0, feat0, N, 256, 256, ei, E, EA, rowptr, pos, col, gEA);
  // 6) gat0 (C=64, LOGS=8, V=4, D=4)
  fused_gat_h2<64, 8, 4, 4, true, true><<<gNode, blk, 0, stream>>>(
      rowptr, col, feat0, att0, b0, ha, nullptr, N);
  // 7) gemm1 (128x128 -> 4 col-blocks)
  hgemm_tn<<<dim3(4, gM), blk, 0, stream>>>(ha, Bt1, feat1, N, 512, 128);
  // 8) gat1 (C=128, LOGS=9, V=8, D=4)
  fused_gat_h2<128, 9, 8, 4, false, false><<<gNode, blk, 0, stream>>>(
      rowptr, col, feat1, att1, b1, nullptr, out, N);
}